// Round 1
// baseline (174.187 us; speedup 1.0000x reference)
//
#include <hip/hip_runtime.h>

namespace {

constexpr int kBevH = 188, kBevW = 126, kP = kBevH * kBevW;   // 23688
constexpr int kB = 2, kN = 6, kC = 256, kHf = 48, kWf = 96;
constexpr int kHW = kHf * kWf;                                // 4608
constexpr int kCChunk = 32;

__global__ __launch_bounds__(256) void ipm_project_kernel(
    const float* __restrict__ feats, const float* __restrict__ intr,
    const float* __restrict__ c2c, float* __restrict__ out) {
  const int p = blockIdx.x * 256 + threadIdx.x;
  const int b = blockIdx.y;
  const int c0 = blockIdx.z * kCChunk;
  const bool inrange = p < kP;
  const int pi = p / kBevW;
  const int pj = p - pi * kBevW;

  // BEV cell centers (match linspace(X_MIN+dx/2, X_MAX-dx/2, H) to fp32 eps)
  const float dx = 75.2f / 188.0f;
  const float dy = 50.4f / 126.0f;
  const float xcar = 0.5f * dx + (float)pi * dx;
  const float ycar = -25.2f + 0.5f * dy + (float)pj * dy;

  int tap[kN][4];
  float tw[kN][4];
  int vmask = 0;

  const float* Kb = intr + (size_t)b * kN * 9;
  const float* Mb = c2c + (size_t)b * kN * 16;
#pragma unroll
  for (int n = 0; n < kN; ++n) {
    const float* M = Mb + n * 16;
    const float* K = Kb + n * 9;
    // P_cam = M @ [x, y, 0, 1]
    float Xc = M[0] * xcar + M[1] * ycar + M[3];
    float Yc = M[4] * xcar + M[5] * ycar + M[7];
    float Zc = M[8] * xcar + M[9] * ycar + M[11];
    // p_img = K @ P_cam3
    float u = K[0] * Xc + K[1] * Yc + K[2] * Zc;
    float v = K[3] * Xc + K[4] * Yc + K[5] * Zc;
    float w = K[6] * Xc + K[7] * Yc + K[8] * Zc;
    float z = fmaxf(w, 1e-4f);
    float uf = (u / z) * 0.125f;  // /(IMG_W/Wf) = /8, exact pow2
    float vf = (v / z) * 0.125f;  // /(IMG_H/Hf) = /8
    bool valid = inrange && (Zc > 0.1f) && (uf >= 0.0f) && (uf <= 95.0f) &&
                 (vf >= 0.0f) && (vf <= 47.0f);
    if (valid) {
      // reproduce the norm round-trip op order of the reference
      float un = (uf / 95.0f) * 2.0f - 1.0f;
      float vn = (vf / 47.0f) * 2.0f - 1.0f;
      float ix = (un + 1.0f) * 0.5f * 95.0f;
      float iy = (vn + 1.0f) * 0.5f * 47.0f;
      float x0f = floorf(ix), y0f = floorf(iy);
      float wx1 = ix - x0f, wx0 = 1.0f - wx1;
      float wy1 = iy - y0f, wy0 = 1.0f - wy1;
#pragma unroll
      for (int t = 0; t < 4; ++t) {
        float xf = x0f + (float)(t & 1);
        float yf = y0f + (float)(t >> 1);
        bool inb =
            (xf >= 0.0f) && (xf <= 95.0f) && (yf >= 0.0f) && (yf <= 47.0f);
        int xi = (int)fminf(fmaxf(xf, 0.0f), 95.0f);
        int yi = (int)fminf(fmaxf(yf, 0.0f), 47.0f);
        float wgt = ((t & 1) ? wx1 : wx0) * ((t >> 1) ? wy1 : wy0);
        tap[n][t] = yi * kWf + xi;
        tw[n][t] = inb ? wgt : 0.0f;  // fold OOB-tap zeroing into weight
      }
      vmask |= (1 << n);
    }
  }

  const float inv_n = 1.0f / 6.0f;
#pragma unroll 4
  for (int k = 0; k < kCChunk; ++k) {
    const int c = c0 + k;
    float acc = 0.0f;
#pragma unroll
    for (int n = 0; n < kN; ++n) {
      if (vmask & (1 << n)) {
        const float* f = feats + ((size_t)(b * kN + n) * kC + c) * kHW;
        acc += f[tap[n][0]] * tw[n][0] + f[tap[n][1]] * tw[n][1] +
               f[tap[n][2]] * tw[n][2] + f[tap[n][3]] * tw[n][3];
      }
    }
    if (inrange) out[((size_t)b * kC + c) * kP + p] = acc * inv_n;
  }
}

}  // namespace

extern "C" void kernel_launch(void* const* d_in, const int* in_sizes, int n_in,
                              void* d_out, int out_size, void* d_ws,
                              size_t ws_size, hipStream_t stream) {
  const float* feats = (const float*)d_in[0];
  const float* intr = (const float*)d_in[1];
  const float* c2c = (const float*)d_in[2];
  float* out = (float*)d_out;
  dim3 grid((kP + 255) / 256, kB, kC / kCChunk);
  ipm_project_kernel<<<grid, dim3(256), 0, stream>>>(feats, intr, c2c, out);
}

// Round 2
// 87.739 us; speedup vs baseline: 1.9853x; 1.9853x over previous
//
#include <hip/hip_runtime.h>

namespace {

constexpr int kBevH = 188, kBevW = 126, kP = kBevH * kBevW;   // 23688
constexpr int kB = 2, kN = 6, kC = 256, kHf = 48, kWf = 96;
constexpr int kHW = kHf * kWf;                                // 4608
constexpr size_t kTransposedBytes = (size_t)kB * kN * kHW * kC * 4;  // 56.6 MB

// ---------------- Kernel 1: feats [B,N,C,H,W] -> ws [B,N,H,W,C] ----------
__global__ __launch_bounds__(256) void transpose_feats_kernel(
    const float* __restrict__ src, float* __restrict__ dst) {
  __shared__ float tile[32][33];
  const int m = blockIdx.z;                 // b*6+n
  const int hw0 = blockIdx.x * 32;
  const int c0 = blockIdx.y * 32;
  const int tx = threadIdx.x, ty = threadIdx.y;
  const float* s = src + (size_t)m * kC * kHW;
  float* d = dst + (size_t)m * kHW * kC;
#pragma unroll
  for (int k = 0; k < 4; ++k)
    tile[ty + 8 * k][tx] = s[(size_t)(c0 + ty + 8 * k) * kHW + hw0 + tx];
  __syncthreads();
#pragma unroll
  for (int k = 0; k < 4; ++k)
    d[(size_t)(hw0 + ty + 8 * k) * kC + c0 + tx] = tile[tx][ty + 8 * k];
}

// ---------------- Kernel 2: gather (lane = channel, coalesced) -----------
// Block = 256 thr = 4 waves. Block covers 16 consecutive p, all 256 c.
// Wave w handles p = p0 + 4w + j (j=0..3); lane l holds channels 4l..4l+3.
// Output re-transposed through LDS so out[B,C,P] writes are coalesced.
__global__ __launch_bounds__(256) void ipm_gather_kernel(
    const float* __restrict__ tf, const float* __restrict__ intr,
    const float* __restrict__ c2c, float* __restrict__ out) {
  __shared__ float sm[16][kC];
  const int b = blockIdx.y;
  const int p0 = blockIdx.x * 16;
  const int w = threadIdx.x >> 6, l = threadIdx.x & 63;

  const float* Kb = intr + (size_t)b * kN * 9;
  const float* Mb = c2c + (size_t)b * kN * 16;
  const float dx = 75.2f / 188.0f;
  const float dy = 50.4f / 126.0f;
  const float inv_n = 1.0f / 6.0f;

#pragma unroll
  for (int j = 0; j < 4; ++j) {
    const int p = p0 + 4 * w + j;
    float4 acc = {0.f, 0.f, 0.f, 0.f};
    if (p < kP) {
      const int pi = p / kBevW;
      const int pj = p - pi * kBevW;
      const float xcar = 0.5f * dx + (float)pi * dx;
      const float ycar = -25.2f + 0.5f * dy + (float)pj * dy;
#pragma unroll
      for (int n = 0; n < kN; ++n) {
        const float* M = Mb + n * 16;
        const float* K = Kb + n * 9;
        float Xc = M[0] * xcar + M[1] * ycar + M[3];
        float Yc = M[4] * xcar + M[5] * ycar + M[7];
        float Zc = M[8] * xcar + M[9] * ycar + M[11];
        float u = K[0] * Xc + K[1] * Yc + K[2] * Zc;
        float v = K[3] * Xc + K[4] * Yc + K[5] * Zc;
        float ww = K[6] * Xc + K[7] * Yc + K[8] * Zc;
        float z = fmaxf(ww, 1e-4f);
        float uf = (u / z) * 0.125f;
        float vf = (v / z) * 0.125f;
        bool valid = (Zc > 0.1f) && (uf >= 0.0f) && (uf <= 95.0f) &&
                     (vf >= 0.0f) && (vf <= 47.0f);
        if (valid) {
          // reproduce reference op order (norm round-trip)
          float un = (uf / 95.0f) * 2.0f - 1.0f;
          float vn = (vf / 47.0f) * 2.0f - 1.0f;
          float ix = (un + 1.0f) * 0.5f * 95.0f;
          float iy = (vn + 1.0f) * 0.5f * 47.0f;
          float x0f = floorf(ix), y0f = floorf(iy);
          float wx1 = ix - x0f, wx0 = 1.0f - wx1;
          float wy1 = iy - y0f, wy0 = 1.0f - wy1;
          const float* base =
              tf + ((size_t)(b * kN + n) * kHW) * kC + 4 * l;
#pragma unroll
          for (int t = 0; t < 4; ++t) {
            float xf = x0f + (float)(t & 1);
            float yf = y0f + (float)(t >> 1);
            bool inb = (xf >= 0.0f) && (xf <= 95.0f) && (yf >= 0.0f) &&
                       (yf <= 47.0f);
            int xi = (int)fminf(fmaxf(xf, 0.0f), 95.0f);
            int yi = (int)fminf(fmaxf(yf, 0.0f), 47.0f);
            float wgt = ((t & 1) ? wx1 : wx0) * ((t >> 1) ? wy1 : wy0);
            wgt = inb ? wgt : 0.0f;
            const float4 val =
                *(const float4*)(base + (size_t)(yi * kWf + xi) * kC);
            acc.x += wgt * val.x;
            acc.y += wgt * val.y;
            acc.z += wgt * val.z;
            acc.w += wgt * val.w;
          }
        }
      }
    }
    acc.x *= inv_n; acc.y *= inv_n; acc.z *= inv_n; acc.w *= inv_n;
    *(float4*)&sm[4 * w + j][4 * l] = acc;
  }
  __syncthreads();

  // write phase: thread t owns channel c=t, writes 16 consecutive p
  const int t = threadIdx.x;
  const int nv = min(16, kP - p0);           // 16 or 8 (both %4==0)
  float* ob = out + ((size_t)(b * kC + t)) * kP + p0;
  for (int pp = 0; pp < nv; pp += 4) {
    float4 v = {sm[pp][t], sm[pp + 1][t], sm[pp + 2][t], sm[pp + 3][t]};
    *(float4*)(ob + pp) = v;
  }
}

// ---------------- Fallback (R0 kernel) if ws too small -------------------
constexpr int kCChunk = 32;
__global__ __launch_bounds__(256) void ipm_project_kernel(
    const float* __restrict__ feats, const float* __restrict__ intr,
    const float* __restrict__ c2c, float* __restrict__ out) {
  const int p = blockIdx.x * 256 + threadIdx.x;
  const int b = blockIdx.y;
  const int c0 = blockIdx.z * kCChunk;
  const bool inrange = p < kP;
  const int pi = p / kBevW;
  const int pj = p - pi * kBevW;
  const float dx = 75.2f / 188.0f;
  const float dy = 50.4f / 126.0f;
  const float xcar = 0.5f * dx + (float)pi * dx;
  const float ycar = -25.2f + 0.5f * dy + (float)pj * dy;
  int tap[kN][4];
  float tw[kN][4];
  int vmask = 0;
  const float* Kb = intr + (size_t)b * kN * 9;
  const float* Mb = c2c + (size_t)b * kN * 16;
#pragma unroll
  for (int n = 0; n < kN; ++n) {
    const float* M = Mb + n * 16;
    const float* K = Kb + n * 9;
    float Xc = M[0] * xcar + M[1] * ycar + M[3];
    float Yc = M[4] * xcar + M[5] * ycar + M[7];
    float Zc = M[8] * xcar + M[9] * ycar + M[11];
    float u = K[0] * Xc + K[1] * Yc + K[2] * Zc;
    float v = K[3] * Xc + K[4] * Yc + K[5] * Zc;
    float w = K[6] * Xc + K[7] * Yc + K[8] * Zc;
    float z = fmaxf(w, 1e-4f);
    float uf = (u / z) * 0.125f;
    float vf = (v / z) * 0.125f;
    bool valid = inrange && (Zc > 0.1f) && (uf >= 0.0f) && (uf <= 95.0f) &&
                 (vf >= 0.0f) && (vf <= 47.0f);
    if (valid) {
      float un = (uf / 95.0f) * 2.0f - 1.0f;
      float vn = (vf / 47.0f) * 2.0f - 1.0f;
      float ix = (un + 1.0f) * 0.5f * 95.0f;
      float iy = (vn + 1.0f) * 0.5f * 47.0f;
      float x0f = floorf(ix), y0f = floorf(iy);
      float wx1 = ix - x0f, wx0 = 1.0f - wx1;
      float wy1 = iy - y0f, wy0 = 1.0f - wy1;
#pragma unroll
      for (int t = 0; t < 4; ++t) {
        float xf = x0f + (float)(t & 1);
        float yf = y0f + (float)(t >> 1);
        bool inb =
            (xf >= 0.0f) && (xf <= 95.0f) && (yf >= 0.0f) && (yf <= 47.0f);
        int xi = (int)fminf(fmaxf(xf, 0.0f), 95.0f);
        int yi = (int)fminf(fmaxf(yf, 0.0f), 47.0f);
        float wgt = ((t & 1) ? wx1 : wx0) * ((t >> 1) ? wy1 : wy0);
        tap[n][t] = yi * kWf + xi;
        tw[n][t] = inb ? wgt : 0.0f;
      }
      vmask |= (1 << n);
    }
  }
  const float inv_n = 1.0f / 6.0f;
#pragma unroll 4
  for (int k = 0; k < kCChunk; ++k) {
    const int c = c0 + k;
    float acc = 0.0f;
#pragma unroll
    for (int n = 0; n < kN; ++n) {
      if (vmask & (1 << n)) {
        const float* f = feats + ((size_t)(b * kN + n) * kC + c) * kHW;
        acc += f[tap[n][0]] * tw[n][0] + f[tap[n][1]] * tw[n][1] +
               f[tap[n][2]] * tw[n][2] + f[tap[n][3]] * tw[n][3];
      }
    }
    if (inrange) out[((size_t)b * kC + c) * kP + p] = acc * inv_n;
  }
}

}  // namespace

extern "C" void kernel_launch(void* const* d_in, const int* in_sizes, int n_in,
                              void* d_out, int out_size, void* d_ws,
                              size_t ws_size, hipStream_t stream) {
  const float* feats = (const float*)d_in[0];
  const float* intr = (const float*)d_in[1];
  const float* c2c = (const float*)d_in[2];
  float* out = (float*)d_out;

  if (ws_size >= kTransposedBytes && d_ws != nullptr) {
    float* tf = (float*)d_ws;
    // K1: transpose feats to channel-last
    dim3 g1(kHW / 32, kC / 32, kB * kN);
    transpose_feats_kernel<<<g1, dim3(32, 8), 0, stream>>>(feats, tf);
    // K2: coalesced gather + in-block output transpose
    dim3 g2((kP + 15) / 16, kB);
    ipm_gather_kernel<<<g2, dim3(256), 0, stream>>>(tf, intr, c2c, out);
  } else {
    dim3 grid((kP + 255) / 256, kB, kC / kCChunk);
    ipm_project_kernel<<<grid, dim3(256), 0, stream>>>(feats, intr, c2c, out);
  }
}

// Round 3
// 86.587 us; speedup vs baseline: 2.0117x; 1.0133x over previous
//
#include <hip/hip_runtime.h>

namespace {

constexpr int kBevH = 188, kBevW = 126, kP = kBevH * kBevW;   // 23688
constexpr int kB = 2, kN = 6, kC = 256, kHf = 48, kWf = 96;
constexpr int kHW = kHf * kWf;                                // 4608
constexpr size_t kTransposedBytes = (size_t)kB * kN * kHW * kC * 4;  // 56.6 MB

// ---------------- Kernel 1: feats [B,N,C,H,W] -> ws [B,N,H,W,C] ----------
__global__ __launch_bounds__(256) void transpose_feats_kernel(
    const float* __restrict__ src, float* __restrict__ dst) {
  __shared__ float tile[32][33];
  const int m = blockIdx.z;                 // b*6+n
  const int hw0 = blockIdx.x * 32;
  const int c0 = blockIdx.y * 32;
  const int tx = threadIdx.x, ty = threadIdx.y;
  const float* s = src + (size_t)m * kC * kHW;
  float* d = dst + (size_t)m * kHW * kC;
#pragma unroll
  for (int k = 0; k < 4; ++k)
    tile[ty + 8 * k][tx] = s[(size_t)(c0 + ty + 8 * k) * kHW + hw0 + tx];
  __syncthreads();
#pragma unroll
  for (int k = 0; k < 4; ++k)
    d[(size_t)(hw0 + ty + 8 * k) * kC + c0 + tx] = tile[tx][ty + 8 * k];
}

// ---------------- Kernel 2: hybrid-lane gather ---------------------------
// Block = 256 thr = 4 waves; block covers 32 consecutive p, all 256 c.
// Wave w: p = p0 + 8*w + (lane>>3)  (8 p-groups), c-lane = lane&7.
// Projection computed ONCE per wave (lane-parallel over 8 p, only 8x
// redundant), taps/weights held in registers, reused across 8 c-iters.
// Each 8-lane group's float4 load = one aligned 128B line.
__global__ __launch_bounds__(256) void ipm_gather_kernel(
    const float* __restrict__ tf, const float* __restrict__ intr,
    const float* __restrict__ c2c, float* __restrict__ out) {
  const int b = blockIdx.y;
  const int p0 = blockIdx.x * 32;
  const int tid = threadIdx.x;
  const int w = tid >> 6;
  const int l = tid & 63;
  const int g = l >> 3;   // p-group within wave
  const int cl = l & 7;   // c-lane within group
  const int p = p0 + 8 * w + g;

  const float dx = 75.2f / 188.0f;
  const float dy = 50.4f / 126.0f;
  const float inv_n = 1.0f / 6.0f;
  const float* Kb = intr + (size_t)b * kN * 9;
  const float* Mb = c2c + (size_t)b * kN * 16;

  int offs[kN][4];
  float wts[kN][4];
  int vmask = 0;

  if (p < kP) {
    const int pi = p / kBevW;
    const int pj = p - pi * kBevW;
    const float xcar = 0.5f * dx + (float)pi * dx;
    const float ycar = -25.2f + 0.5f * dy + (float)pj * dy;
#pragma unroll
    for (int n = 0; n < kN; ++n) {
      const float* M = Mb + n * 16;
      const float* K = Kb + n * 9;
      float Xc = M[0] * xcar + M[1] * ycar + M[3];
      float Yc = M[4] * xcar + M[5] * ycar + M[7];
      float Zc = M[8] * xcar + M[9] * ycar + M[11];
      float u = K[0] * Xc + K[1] * Yc + K[2] * Zc;
      float v = K[3] * Xc + K[4] * Yc + K[5] * Zc;
      float ww = K[6] * Xc + K[7] * Yc + K[8] * Zc;
      float z = fmaxf(ww, 1e-4f);
      float uf = (u / z) * 0.125f;
      float vf = (v / z) * 0.125f;
      bool valid = (Zc > 0.1f) && (uf >= 0.0f) && (uf <= 95.0f) &&
                   (vf >= 0.0f) && (vf <= 47.0f);
      if (valid) {
        // reproduce reference op order (norm round-trip)
        float un = (uf / 95.0f) * 2.0f - 1.0f;
        float vn = (vf / 47.0f) * 2.0f - 1.0f;
        float ix = (un + 1.0f) * 0.5f * 95.0f;
        float iy = (vn + 1.0f) * 0.5f * 47.0f;
        float x0f = floorf(ix), y0f = floorf(iy);
        float wx1 = ix - x0f, wx0 = 1.0f - wx1;
        float wy1 = iy - y0f, wy0 = 1.0f - wy1;
#pragma unroll
        for (int t = 0; t < 4; ++t) {
          float xf = x0f + (float)(t & 1);
          float yf = y0f + (float)(t >> 1);
          bool inb = (xf >= 0.0f) && (xf <= 95.0f) && (yf >= 0.0f) &&
                     (yf <= 47.0f);
          int xi = (int)fminf(fmaxf(xf, 0.0f), 95.0f);
          int yi = (int)fminf(fmaxf(yf, 0.0f), 47.0f);
          float wgt = ((t & 1) ? wx1 : wx0) * ((t >> 1) ? wy1 : wy0);
          offs[n][t] = (yi * kWf + xi) * kC;
          wts[n][t] = inb ? wgt : 0.0f;
        }
        vmask |= (1 << n);
      } else {
#pragma unroll
        for (int t = 0; t < 4; ++t) { offs[n][t] = 0; wts[n][t] = 0.0f; }
      }
    }
  } else {
#pragma unroll
    for (int n = 0; n < kN; ++n)
#pragma unroll
      for (int t = 0; t < 4; ++t) { offs[n][t] = 0; wts[n][t] = 0.0f; }
  }

#pragma unroll 2
  for (int ci = 0; ci < 8; ++ci) {
    const int c = ci * 32 + 4 * cl;
    float ax = 0.f, ay = 0.f, az = 0.f, aw = 0.f;
#pragma unroll
    for (int n = 0; n < kN; ++n) {
      if (vmask & (1 << n)) {
        const float* fb = tf + ((size_t)(b * kN + n) * kHW) * kC + c;
#pragma unroll
        for (int t = 0; t < 4; ++t) {
          const float4 v = *(const float4*)(fb + offs[n][t]);
          const float wt = wts[n][t];
          ax += wt * v.x; ay += wt * v.y; az += wt * v.z; aw += wt * v.w;
        }
      }
    }
    if (p < kP) {
      float* ob = out + ((size_t)(b * kC + c)) * kP + p;
      ob[0]          = ax * inv_n;
      ob[kP]         = ay * inv_n;
      ob[2 * (size_t)kP] = az * inv_n;
      ob[3 * (size_t)kP] = aw * inv_n;
    }
  }
}

// ---------------- Fallback (R0 kernel) if ws too small -------------------
constexpr int kCChunk = 32;
__global__ __launch_bounds__(256) void ipm_project_kernel(
    const float* __restrict__ feats, const float* __restrict__ intr,
    const float* __restrict__ c2c, float* __restrict__ out) {
  const int p = blockIdx.x * 256 + threadIdx.x;
  const int b = blockIdx.y;
  const int c0 = blockIdx.z * kCChunk;
  const bool inrange = p < kP;
  const int pi = p / kBevW;
  const int pj = p - pi * kBevW;
  const float dx = 75.2f / 188.0f;
  const float dy = 50.4f / 126.0f;
  const float xcar = 0.5f * dx + (float)pi * dx;
  const float ycar = -25.2f + 0.5f * dy + (float)pj * dy;
  int tap[kN][4];
  float tw[kN][4];
  int vmask = 0;
  const float* Kb = intr + (size_t)b * kN * 9;
  const float* Mb = c2c + (size_t)b * kN * 16;
#pragma unroll
  for (int n = 0; n < kN; ++n) {
    const float* M = Mb + n * 16;
    const float* K = Kb + n * 9;
    float Xc = M[0] * xcar + M[1] * ycar + M[3];
    float Yc = M[4] * xcar + M[5] * ycar + M[7];
    float Zc = M[8] * xcar + M[9] * ycar + M[11];
    float u = K[0] * Xc + K[1] * Yc + K[2] * Zc;
    float v = K[3] * Xc + K[4] * Yc + K[5] * Zc;
    float w = K[6] * Xc + K[7] * Yc + K[8] * Zc;
    float z = fmaxf(w, 1e-4f);
    float uf = (u / z) * 0.125f;
    float vf = (v / z) * 0.125f;
    bool valid = inrange && (Zc > 0.1f) && (uf >= 0.0f) && (uf <= 95.0f) &&
                 (vf >= 0.0f) && (vf <= 47.0f);
    if (valid) {
      float un = (uf / 95.0f) * 2.0f - 1.0f;
      float vn = (vf / 47.0f) * 2.0f - 1.0f;
      float ix = (un + 1.0f) * 0.5f * 95.0f;
      float iy = (vn + 1.0f) * 0.5f * 47.0f;
      float x0f = floorf(ix), y0f = floorf(iy);
      float wx1 = ix - x0f, wx0 = 1.0f - wx1;
      float wy1 = iy - y0f, wy0 = 1.0f - wy1;
#pragma unroll
      for (int t = 0; t < 4; ++t) {
        float xf = x0f + (float)(t & 1);
        float yf = y0f + (float)(t >> 1);
        bool inb =
            (xf >= 0.0f) && (xf <= 95.0f) && (yf >= 0.0f) && (yf <= 47.0f);
        int xi = (int)fminf(fmaxf(xf, 0.0f), 95.0f);
        int yi = (int)fminf(fmaxf(yf, 0.0f), 47.0f);
        float wgt = ((t & 1) ? wx1 : wx0) * ((t >> 1) ? wy1 : wy0);
        tap[n][t] = yi * kWf + xi;
        tw[n][t] = inb ? wgt : 0.0f;
      }
      vmask |= (1 << n);
    }
  }
  const float inv_n = 1.0f / 6.0f;
#pragma unroll 4
  for (int k = 0; k < kCChunk; ++k) {
    const int c = c0 + k;
    float acc = 0.0f;
#pragma unroll
    for (int n = 0; n < kN; ++n) {
      if (vmask & (1 << n)) {
        const float* f = feats + ((size_t)(b * kN + n) * kC + c) * kHW;
        acc += f[tap[n][0]] * tw[n][0] + f[tap[n][1]] * tw[n][1] +
               f[tap[n][2]] * tw[n][2] + f[tap[n][3]] * tw[n][3];
      }
    }
    if (inrange) out[((size_t)b * kC + c) * kP + p] = acc * inv_n;
  }
}

}  // namespace

extern "C" void kernel_launch(void* const* d_in, const int* in_sizes, int n_in,
                              void* d_out, int out_size, void* d_ws,
                              size_t ws_size, hipStream_t stream) {
  const float* feats = (const float*)d_in[0];
  const float* intr = (const float*)d_in[1];
  const float* c2c = (const float*)d_in[2];
  float* out = (float*)d_out;

  if (ws_size >= kTransposedBytes && d_ws != nullptr) {
    float* tf = (float*)d_ws;
    dim3 g1(kHW / 32, kC / 32, kB * kN);
    transpose_feats_kernel<<<g1, dim3(32, 8), 0, stream>>>(feats, tf);
    dim3 g2((kP + 31) / 32, kB);
    ipm_gather_kernel<<<g2, dim3(256), 0, stream>>>(tf, intr, c2c, out);
  } else {
    dim3 grid((kP + 255) / 256, kB, kC / kCChunk);
    ipm_project_kernel<<<grid, dim3(256), 0, stream>>>(feats, intr, c2c, out);
  }
}